// Round 5
// baseline (84.658 us; speedup 1.0000x reference)
//
#include <hip/hip_runtime.h>
#include <math.h>

static constexpr int Bb   = 16;
static constexpr int Ww   = 256;
static constexpr int HWp  = 256 * 256;   // 65536 pixels per batch row
static constexpr int CF   = 128;
static constexpr int THREADS = 1024;
static constexpr int NWAVE = THREADS / 64;  // 16 waves

// Strict total order matching jax.lax.top_k: value descending, index ascending on ties.
__device__ __forceinline__ bool better(float v1, int i1, float v2, int i2) {
    return (v1 > v2) || ((v1 == v2) && (i1 < i2));
}

__device__ __forceinline__ void upd(float v, int p,
                                    float& v0, int& i0, float& v1, int& i1) {
    if (better(v, p, v0, i0)) { v1 = v0; i1 = i0; v0 = v; i0 = p; }
    else if (better(v, p, v1, i1)) { v1 = v; i1 = p; }
}

// merge sorted pair (b0,b1) into sorted pair (a0,a1)
__device__ __forceinline__ void merge2(float& a0, int& ia0, float& a1, int& ia1,
                                       float b0, int ib0, float b1, int ib1) {
    if (better(b0, ib0, a0, ia0)) {
        float na1; int nia1;
        if (better(a0, ia0, b1, ib1)) { na1 = a0; nia1 = ia0; }
        else                          { na1 = b1; nia1 = ib1; }
        a0 = b0; ia0 = ib0; a1 = na1; ia1 = nia1;
    } else if (better(b0, ib0, a1, ia1)) {
        a1 = b0; ia1 = ib0;
    }
}

// One block per batch b. Block-local dual-class top-2 over the full 65536-pixel
// row, then this block writes every output belonging to its 4 points
// (c,j in {0,1}^2, pi = c*32 + b*2 + j). No workspace, no atomics, no
// cross-block communication -> single graph node, deterministic by construction.
__global__ __launch_bounds__(THREADS) void genpixel_onepass(
    const float* __restrict__ infeat,
    const float* __restrict__ labelTpesudo,
    const float* __restrict__ labelT,
    const float* __restrict__ FeatureDA,
    float* __restrict__ out)
{
    const int b = blockIdx.x;    // 0..15
    const int t = threadIdx.x;   // 0..1023
    const float* x0p = infeat + ((size_t)b * 2 + 0) * HWp;
    const float* x1p = infeat + ((size_t)b * 2 + 1) * HWp;

    // class-0 list (value e0/s) and class-1 list (value e1/s)
    float u0 = -INFINITY, u1 = -INFINITY;  int ui0 = 0x7fffffff, ui1 = 0x7fffffff;
    float w0 = -INFINITY, w1 = -INFINITY;  int wi0 = 0x7fffffff, wi1 = 0x7fffffff;

    #pragma unroll
    for (int it = 0; it < HWp / (THREADS * 4); ++it) {   // 16 iterations
        const int p = it * (THREADS * 4) + t * 4;
        const float4 a  = *(const float4*)(x0p + p);
        const float4 bb = *(const float4*)(x1p + p);
        const float ax[4] = {a.x, a.y, a.z, a.w};
        const float bx[4] = {bb.x, bb.y, bb.z, bb.w};
        #pragma unroll
        for (int e = 0; e < 4; ++e) {
            const float m  = fmaxf(ax[e], bx[e]);
            const float e0 = expf(ax[e] - m);
            const float e1 = expf(bx[e] - m);
            const float s  = e0 + e1;
            const float va = e0 / s;     // bit-exact vs reference formula (absmax 0.0 R1-R3)
            const float vb = e1 / s;
            const int gp = p + e;
            upd(va, gp, u0, ui0, u1, ui1);
            upd(vb, gp, w0, wi0, w1, wi1);
        }
    }

    // 64-lane in-register butterfly reduction
    #pragma unroll
    for (int m = 1; m < 64; m <<= 1) {
        float ou0 = __shfl_xor(u0, m), ou1 = __shfl_xor(u1, m);
        int  oui0 = __shfl_xor(ui0, m), oui1 = __shfl_xor(ui1, m);
        float ow0 = __shfl_xor(w0, m), ow1 = __shfl_xor(w1, m);
        int  owi0 = __shfl_xor(wi0, m), owi1 = __shfl_xor(wi1, m);
        merge2(u0, ui0, u1, ui1, ou0, oui0, ou1, oui1);
        merge2(w0, wi0, w1, wi1, ow0, owi0, ow1, owi1);
    }

    // cross-wave merge: 16 wave partials -> LDS -> t0
    __shared__ float sv[NWAVE][2][2];
    __shared__ int   si[NWAVE][2][2];
    const int wave = t >> 6;
    if ((t & 63) == 0) {
        sv[wave][0][0] = u0; sv[wave][0][1] = u1;
        sv[wave][1][0] = w0; sv[wave][1][1] = w1;
        si[wave][0][0] = ui0; si[wave][0][1] = ui1;
        si[wave][1][0] = wi0; si[wave][1][1] = wi1;
    }
    __syncthreads();

    __shared__ int   p_idx[4];    // local point l = c*2 + j
    __shared__ float p_val[4];
    if (t == 0) {
        float a0 = sv[0][0][0], a1 = sv[0][0][1];
        int  ia0 = si[0][0][0], ia1 = si[0][0][1];
        float c0 = sv[0][1][0], c1 = sv[0][1][1];
        int  ic0 = si[0][1][0], ic1 = si[0][1][1];
        #pragma unroll
        for (int wv = 1; wv < NWAVE; ++wv) {
            merge2(a0, ia0, a1, ia1, sv[wv][0][0], si[wv][0][0], sv[wv][0][1], si[wv][0][1]);
            merge2(c0, ic0, c1, ic1, sv[wv][1][0], si[wv][1][0], sv[wv][1][1], si[wv][1][1]);
        }
        p_val[0] = a0; p_idx[0] = ia0;   // c=0, j=0
        p_val[1] = a1; p_idx[1] = ia1;   // c=0, j=1
        p_val[2] = c0; p_idx[2] = ic0;   // c=1, j=0
        p_val[3] = c1; p_idx[3] = ic1;   // c=1, j=1
    }
    __syncthreads();

    // ---- outputs for this block's 4 points; pi = (l>>1)*32 + b*2 + (l&1) ----
    // Output layout (flat float32, 8768 elems):
    //   [0,128) classiferT (64,2) | [128,8320) patchFeatDA (64,128)
    //   [8320,8384) labelTTrue | [8384,8448) labelpesudo | [8448,8512) provalue
    //   [8512,8768) pointXY (64,2,2) = [px, min(px+31,255), py, min(py+31,255)]
    if (t < 4 * CF) {                       // 512 threads: 4 points x 128 channels
        const int l  = t >> 7;              // local point
        const int ch = t & 127;
        const int pi = (l >> 1) * 32 + b * 2 + (l & 1);
        const int idx = p_idx[l];
        out[128 + pi * CF + ch] = FeatureDA[((size_t)b * CF + ch) * HWp + idx];
    }
    if (t < 4) {
        const int l  = t;
        const int pi = (l >> 1) * 32 + b * 2 + (l & 1);
        const int idx = p_idx[l];
        const int py = idx >> 8;
        const int px = idx & (Ww - 1);
        out[pi * 2 + 0] = x0p[idx];
        out[pi * 2 + 1] = x1p[idx];
        out[8320 + pi] = labelT[(size_t)b * HWp + idx];
        out[8384 + pi] = labelTpesudo[(size_t)b * HWp + idx];
        out[8448 + pi] = p_val[l];
        out[8512 + pi * 4 + 0] = (float)px;
        out[8512 + pi * 4 + 1] = (float)min(px + 31, 255);
        out[8512 + pi * 4 + 2] = (float)py;
        out[8512 + pi * 4 + 3] = (float)min(py + 31, 255);
    }
}

extern "C" void kernel_launch(void* const* d_in, const int* in_sizes, int n_in,
                              void* d_out, int out_size, void* d_ws, size_t ws_size,
                              hipStream_t stream) {
    const float* infeat       = (const float*)d_in[0];
    const float* labelTpesudo = (const float*)d_in[1];
    const float* labelT       = (const float*)d_in[2];
    const float* FeatureDA    = (const float*)d_in[3];
    float* out = (float*)d_out;
    (void)in_sizes; (void)n_in; (void)d_ws; (void)ws_size; (void)out_size;

    genpixel_onepass<<<Bb, THREADS, 0, stream>>>(
        infeat, labelTpesudo, labelT, FeatureDA, out);
}

// Round 6
// 26.848 us; speedup vs baseline: 3.1533x; 3.1533x over previous
//
#include <hip/hip_runtime.h>
#include <math.h>

static constexpr int Bb   = 16;
static constexpr int Ww   = 256;
static constexpr int HWp  = 256 * 256;   // 65536
static constexpr int CF   = 128;
static constexpr int Kk   = 2;
static constexpr int SEGS = 32;
static constexpr int SEGLEN = HWp / SEGS;   // 2048 pixels per block
static constexpr int THREADS = 256;

// Strict total order matching jax.lax.top_k: value descending, index ascending on ties.
__device__ __forceinline__ bool better(float v1, int i1, float v2, int i2) {
    return (v1 > v2) || ((v1 == v2) && (i1 < i2));
}

__device__ __forceinline__ void upd(float v, int p,
                                    float& v0, int& i0, float& v1, int& i1) {
    if (better(v, p, v0, i0)) { v1 = v0; i1 = i0; v0 = v; i0 = p; }
    else if (better(v, p, v1, i1)) { v1 = v; i1 = p; }
}

// merge sorted pair (b0,b1) into sorted pair (a0,a1)
__device__ __forceinline__ void merge2(float& a0, int& ia0, float& a1, int& ia1,
                                       float b0, int ib0, float b1, int ib1) {
    if (better(b0, ib0, a0, ia0)) {
        float na1; int nia1;
        if (better(a0, ia0, b1, ib1)) { na1 = a0; nia1 = ia0; }
        else                          { na1 = b1; nia1 = ib1; }
        a0 = b0; ia0 = ib0; a1 = na1; ia1 = nia1;
    } else if (better(b0, ib0, a1, ia1)) {
        a1 = b0; ia1 = ib0;
    }
}

// Stage 1: one block per (batch, segment). Reads both channel planes ONCE,
// computes the 2-class softmax once per pixel, maintains top-2 lists for BOTH
// classes. 512 blocks -> 2 blocks/CU.
__global__ __launch_bounds__(THREADS) void top2_partial(
    const float* __restrict__ infeat, float* __restrict__ ws_v, int* __restrict__ ws_i)
{
    const int b   = blockIdx.x;   // 0..15
    const int seg = blockIdx.y;   // 0..SEGS-1
    const int t   = threadIdx.x;
    const float* x0p = infeat + ((size_t)b * 2 + 0) * HWp + seg * SEGLEN;
    const float* x1p = infeat + ((size_t)b * 2 + 1) * HWp + seg * SEGLEN;

    float u0 = -INFINITY, u1 = -INFINITY;  int ui0 = 0x7fffffff, ui1 = 0x7fffffff;
    float w0 = -INFINITY, w1 = -INFINITY;  int wi0 = 0x7fffffff, wi1 = 0x7fffffff;

    #pragma unroll
    for (int it = 0; it < SEGLEN / (THREADS * 4); ++it) {   // 2 iterations
        const int p = it * (THREADS * 4) + t * 4;
        const float4 a  = *(const float4*)(x0p + p);
        const float4 bb = *(const float4*)(x1p + p);
        const float ax[4] = {a.x, a.y, a.z, a.w};
        const float bx[4] = {bb.x, bb.y, bb.z, bb.w};
        #pragma unroll
        for (int e = 0; e < 4; ++e) {
            const float m  = fmaxf(ax[e], bx[e]);
            const float e0 = expf(ax[e] - m);
            const float e1 = expf(bx[e] - m);
            const float s  = e0 + e1;
            const float va = e0 / s;     // bit-exact vs reference formula
            const float vb = e1 / s;
            const int gp = seg * SEGLEN + p + e;
            upd(va, gp, u0, ui0, u1, ui1);
            upd(vb, gp, w0, wi0, w1, wi1);
        }
    }

    // 64-lane in-register butterfly
    #pragma unroll
    for (int m = 1; m < 64; m <<= 1) {
        float ou0 = __shfl_xor(u0, m), ou1 = __shfl_xor(u1, m);
        int  oui0 = __shfl_xor(ui0, m), oui1 = __shfl_xor(ui1, m);
        float ow0 = __shfl_xor(w0, m), ow1 = __shfl_xor(w1, m);
        int  owi0 = __shfl_xor(wi0, m), owi1 = __shfl_xor(wi1, m);
        merge2(u0, ui0, u1, ui1, ou0, oui0, ou1, oui1);
        merge2(w0, wi0, w1, wi1, ow0, owi0, ow1, owi1);
    }

    // cross-wave: 4 wave partials -> LDS -> t0 merges
    __shared__ float sv[4][2][2];
    __shared__ int   si[4][2][2];
    const int wave = t >> 6;
    if ((t & 63) == 0) {
        sv[wave][0][0] = u0; sv[wave][0][1] = u1;
        sv[wave][1][0] = w0; sv[wave][1][1] = w1;
        si[wave][0][0] = ui0; si[wave][0][1] = ui1;
        si[wave][1][0] = wi0; si[wave][1][1] = wi1;
    }
    __syncthreads();
    if (t == 0) {
        #pragma unroll
        for (int wv = 1; wv < 4; ++wv) {
            merge2(sv[0][0][0], si[0][0][0], sv[0][0][1], si[0][0][1],
                   sv[wv][0][0], si[wv][0][0], sv[wv][0][1], si[wv][0][1]);
            merge2(sv[0][1][0], si[0][1][0], sv[0][1][1], si[0][1][1],
                   sv[wv][1][0], si[wv][1][0], sv[wv][1][1], si[wv][1][1]);
        }
        // ws layout: [b][seg][cls][entry]
        const int base = ((b * SEGS + seg) * 2) * 2;
        ws_v[base + 0] = sv[0][0][0]; ws_v[base + 1] = sv[0][0][1];
        ws_v[base + 2] = sv[0][1][0]; ws_v[base + 3] = sv[0][1][1];
        ws_i[base + 0] = si[0][0][0]; ws_i[base + 1] = si[0][0][1];
        ws_i[base + 2] = si[0][1][0]; ws_i[base + 3] = si[0][1][1];
    }
}

// Stage 2: one block per output point pi = c*B*k + b*k + j (64 points), 128 threads.
__global__ __launch_bounds__(128) void gather_out(
    const float* __restrict__ infeat,
    const float* __restrict__ labelTpesudo,
    const float* __restrict__ labelT,
    const float* __restrict__ FeatureDA,
    const float* __restrict__ ws_v, const int* __restrict__ ws_i,
    float* __restrict__ out)
{
    const int pi = blockIdx.x;           // 0..63
    const int c  = pi / (Bb * Kk);
    const int b  = (pi / Kk) % Bb;
    const int j  = pi % Kk;

    __shared__ float s_val;
    __shared__ int   s_idx;
    if (threadIdx.x == 0) {
        float bv0 = -INFINITY, bv1 = -INFINITY;
        int   bi0 = 0x7fffffff, bi1 = 0x7fffffff;
        for (int s2 = 0; s2 < SEGS; ++s2) {
            const int base = ((b * SEGS + s2) * 2 + c) * 2;
            #pragma unroll
            for (int e = 0; e < 2; ++e) {
                const float v = ws_v[base + e];
                const int   i = ws_i[base + e];
                if (better(v, i, bv0, bi0)) { bv1 = bv0; bi1 = bi0; bv0 = v; bi0 = i; }
                else if (better(v, i, bv1, bi1)) { bv1 = v; bi1 = i; }
            }
        }
        s_val = (j == 0) ? bv0 : bv1;
        s_idx = (j == 0) ? bi0 : bi1;
    }
    __syncthreads();

    const int   idx = s_idx;
    const float val = s_val;
    const int py = idx >> 8;        // idx / W
    const int px = idx & (Ww - 1);  // idx % W
    const int t = threadIdx.x;

    // Output layout (flat float32, 8768 elems):
    //   [0,128) classiferT (64,2) | [128,8320) patchFeatDA (64,128)
    //   [8320,8384) labelTTrue | [8384,8448) labelpesudo | [8448,8512) provalue
    //   [8512,8768) pointXY (64,2,2) = [px, min(px+31,255), py, min(py+31,255)]
    out[128 + pi * CF + t] = FeatureDA[((size_t)b * CF + t) * HWp + idx];
    if (t < 2) out[pi * 2 + t] = infeat[((size_t)b * 2 + t) * HWp + idx];
    if (t == 0) {
        out[8320 + pi] = labelT[(size_t)b * HWp + idx];
        out[8384 + pi] = labelTpesudo[(size_t)b * HWp + idx];
        out[8448 + pi] = val;
        out[8512 + pi * 4 + 0] = (float)px;
        out[8512 + pi * 4 + 1] = (float)min(px + 31, 255);
        out[8512 + pi * 4 + 2] = (float)py;
        out[8512 + pi * 4 + 3] = (float)min(py + 31, 255);
    }
}

extern "C" void kernel_launch(void* const* d_in, const int* in_sizes, int n_in,
                              void* d_out, int out_size, void* d_ws, size_t ws_size,
                              hipStream_t stream) {
    const float* infeat       = (const float*)d_in[0];
    const float* labelTpesudo = (const float*)d_in[1];
    const float* labelT       = (const float*)d_in[2];
    const float* FeatureDA    = (const float*)d_in[3];
    float* out = (float*)d_out;

    float* ws_v = (float*)d_ws;                                     // 16*SEGS*4 floats
    int*   ws_i = (int*)((char*)d_ws + Bb * SEGS * 4 * sizeof(float));

    dim3 g1(Bb, SEGS);   // 16 x 32 = 512 blocks
    top2_partial<<<g1, THREADS, 0, stream>>>(infeat, ws_v, ws_i);
    gather_out<<<64, 128, 0, stream>>>(infeat, labelTpesudo, labelT, FeatureDA,
                                       ws_v, ws_i, out);
}

// Round 7
// 17.965 us; speedup vs baseline: 4.7125x; 1.4945x over previous
//
#include <hip/hip_runtime.h>
#include <math.h>

static constexpr int Bb   = 16;
static constexpr int Ww   = 256;
static constexpr int HWp  = 256 * 256;   // 65536
static constexpr int CF   = 128;
static constexpr int Kk   = 2;
static constexpr int SEGS = 8;
static constexpr int SEGLEN = HWp / SEGS; // 8192

// Strict total order matching jax.lax.top_k: value descending, index ascending on ties.
__device__ __forceinline__ bool better(float v1, int i1, float v2, int i2) {
    return (v1 > v2) || ((v1 == v2) && (i1 < i2));
}

// Stage 1: per (row, seg) partial top-2 of softmax(infeat, axis=1) channel `c`.
// row = b*2 + c; 32 rows x SEGS segments.
__global__ __launch_bounds__(256) void top2_partial(
    const float* __restrict__ infeat, float* __restrict__ ws_v, int* __restrict__ ws_i)
{
    const int row = blockIdx.x;        // 0..31
    const int seg = blockIdx.y;        // 0..SEGS-1
    const int b = row >> 1, c = row & 1;
    const float* x0p = infeat + (size_t)(b * 2 + 0) * HWp;
    const float* x1p = infeat + (size_t)(b * 2 + 1) * HWp;
    const int t = threadIdx.x;

    float v0 = -INFINITY, v1 = -INFINITY;
    int   i0 = 0x7fffffff, i1 = 0x7fffffff;

    const int base = seg * SEGLEN + t * 4;
    #pragma unroll
    for (int it = 0; it < SEGLEN / (256 * 4); ++it) {
        const int p = base + it * (256 * 4);
        const float4 a  = *(const float4*)(x0p + p);
        const float4 bb = *(const float4*)(x1p + p);
        const float ax[4] = {a.x, a.y, a.z, a.w};
        const float bx[4] = {bb.x, bb.y, bb.z, bb.w};
        #pragma unroll
        for (int e = 0; e < 4; ++e) {
            const float m  = fmaxf(ax[e], bx[e]);
            const float e0 = expf(ax[e] - m);
            const float e1 = expf(bx[e] - m);
            const float v  = (c == 0 ? e0 : e1) / (e0 + e1);
            const int p2 = p + e;
            if (better(v, p2, v0, i0)) { v1 = v0; i1 = i0; v0 = v; i0 = p2; }
            else if (better(v, p2, v1, i1)) { v1 = v; i1 = p2; }
        }
    }

    __shared__ float sv[256][2];
    __shared__ int   si[256][2];
    sv[t][0] = v0; sv[t][1] = v1; si[t][0] = i0; si[t][1] = i1;
    __syncthreads();
    for (int s = 128; s > 0; s >>= 1) {
        if (t < s) {
            float a0 = sv[t][0], a1 = sv[t][1];
            int  ia0 = si[t][0], ia1 = si[t][1];
            float b0 = sv[t + s][0], b1 = sv[t + s][1];
            int  ib0 = si[t + s][0], ib1 = si[t + s][1];
            float r0, r1; int j0, j1;
            if (better(a0, ia0, b0, ib0)) {
                r0 = a0; j0 = ia0;
                if (better(b0, ib0, a1, ia1)) { r1 = b0; j1 = ib0; } else { r1 = a1; j1 = ia1; }
            } else {
                r0 = b0; j0 = ib0;
                if (better(a0, ia0, b1, ib1)) { r1 = a0; j1 = ia0; } else { r1 = b1; j1 = ib1; }
            }
            sv[t][0] = r0; sv[t][1] = r1; si[t][0] = j0; si[t][1] = j1;
        }
        __syncthreads();
    }
    if (t < 2) {
        ws_v[(row * SEGS + seg) * 2 + t] = sv[0][t];
        ws_i[(row * SEGS + seg) * 2 + t] = si[0][t];
    }
}

// Stage 2: one block per output point pi = c*B*k + b*k + j (64 points), 128 threads.
// Merge the SEGS partial top-2 lists of the row, take entry j, gather + write all outputs.
__global__ __launch_bounds__(128) void gather_out(
    const float* __restrict__ infeat,
    const float* __restrict__ labelTpesudo,
    const float* __restrict__ labelT,
    const float* __restrict__ FeatureDA,
    const float* __restrict__ ws_v, const int* __restrict__ ws_i,
    float* __restrict__ out)
{
    const int pi = blockIdx.x;           // 0..63
    const int c  = pi / (Bb * Kk);
    const int b  = (pi / Kk) % Bb;
    const int j  = pi % Kk;
    const int row = b * 2 + c;

    __shared__ float s_val;
    __shared__ int   s_idx;
    if (threadIdx.x == 0) {
        float bv0 = -INFINITY, bv1 = -INFINITY;
        int   bi0 = 0x7fffffff, bi1 = 0x7fffffff;
        for (int s2 = 0; s2 < SEGS; ++s2) {
            #pragma unroll
            for (int e = 0; e < 2; ++e) {
                const float v = ws_v[(row * SEGS + s2) * 2 + e];
                const int   i = ws_i[(row * SEGS + s2) * 2 + e];
                if (better(v, i, bv0, bi0)) { bv1 = bv0; bi1 = bi0; bv0 = v; bi0 = i; }
                else if (better(v, i, bv1, bi1)) { bv1 = v; bi1 = i; }
            }
        }
        s_val = (j == 0) ? bv0 : bv1;
        s_idx = (j == 0) ? bi0 : bi1;
    }
    __syncthreads();

    const int   idx = s_idx;
    const float val = s_val;
    const int py = idx >> 8;        // idx / W
    const int px = idx & (Ww - 1);  // idx % W
    const int t = threadIdx.x;

    // Output layout (flat float32, 8768 elems):
    //   [0,128)      classiferT   (64,2)
    //   [128,8320)   patchFeatDA  (64,128)
    //   [8320,8384)  labelTTrue   (64,1)
    //   [8384,8448)  labelpesudo  (64,1)
    //   [8448,8512)  provalue     (64,1)
    //   [8512,8768)  pointXY      (64,2,2) -> [px, min(px+31,255), py, min(py+31,255)]
    out[128 + pi * CF + t] = FeatureDA[((size_t)b * CF + t) * HWp + idx];
    if (t < 2) out[pi * 2 + t] = infeat[((size_t)b * 2 + t) * HWp + idx];
    if (t == 0) {
        out[8320 + pi] = labelT[(size_t)b * HWp + idx];
        out[8384 + pi] = labelTpesudo[(size_t)b * HWp + idx];
        out[8448 + pi] = val;
        out[8512 + pi * 4 + 0] = (float)px;
        out[8512 + pi * 4 + 1] = (float)min(px + 31, 255);
        out[8512 + pi * 4 + 2] = (float)py;
        out[8512 + pi * 4 + 3] = (float)min(py + 31, 255);
    }
}

extern "C" void kernel_launch(void* const* d_in, const int* in_sizes, int n_in,
                              void* d_out, int out_size, void* d_ws, size_t ws_size,
                              hipStream_t stream) {
    const float* infeat       = (const float*)d_in[0];
    const float* labelTpesudo = (const float*)d_in[1];
    const float* labelT       = (const float*)d_in[2];
    const float* FeatureDA    = (const float*)d_in[3];
    float* out = (float*)d_out;

    float* ws_v = (float*)d_ws;                                  // 32*SEGS*2 floats
    int*   ws_i = (int*)((char*)d_ws + 32 * SEGS * 2 * sizeof(float));

    dim3 g1(32, SEGS);
    top2_partial<<<g1, 256, 0, stream>>>(infeat, ws_v, ws_i);
    gather_out<<<64, 128, 0, stream>>>(infeat, labelTpesudo, labelT, FeatureDA,
                                       ws_v, ws_i, out);
}

// Round 8
// 17.829 us; speedup vs baseline: 4.7484x; 1.0076x over previous
//
#include <hip/hip_runtime.h>
#include <math.h>

static constexpr int Bb   = 16;
static constexpr int Ww   = 256;
static constexpr int HWp  = 256 * 256;   // 65536
static constexpr int CF   = 128;
static constexpr int Kk   = 2;
static constexpr int SEGS = 8;
static constexpr int SEGLEN = HWp / SEGS; // 8192

// Strict total order matching jax.lax.top_k: value descending, index ascending on ties.
__device__ __forceinline__ bool better(float v1, int i1, float v2, int i2) {
    return (v1 > v2) || ((v1 == v2) && (i1 < i2));
}

// merge sorted pair (b0,b1) into sorted pair (a0,a1)
__device__ __forceinline__ void merge2(float& a0, int& ia0, float& a1, int& ia1,
                                       float b0, int ib0, float b1, int ib1) {
    if (better(b0, ib0, a0, ia0)) {
        float na1; int nia1;
        if (better(a0, ia0, b1, ib1)) { na1 = a0; nia1 = ia0; }
        else                          { na1 = b1; nia1 = ib1; }
        a0 = b0; ia0 = ib0; a1 = na1; ia1 = nia1;
    } else if (better(b0, ib0, a1, ia1)) {
        a1 = b0; ia1 = ib0;
    }
}

// Stage 1: R1/R7 VERBATIM except the reduction: wave butterfly + 4-wave merge
// replaces the 256-thread LDS tree. Single-variable A/B on the reduction method.
__global__ __launch_bounds__(256) void top2_partial(
    const float* __restrict__ infeat, float* __restrict__ ws_v, int* __restrict__ ws_i)
{
    const int row = blockIdx.x;        // 0..31
    const int seg = blockIdx.y;        // 0..SEGS-1
    const int b = row >> 1, c = row & 1;
    const float* x0p = infeat + (size_t)(b * 2 + 0) * HWp;
    const float* x1p = infeat + (size_t)(b * 2 + 1) * HWp;
    const int t = threadIdx.x;

    float v0 = -INFINITY, v1 = -INFINITY;
    int   i0 = 0x7fffffff, i1 = 0x7fffffff;

    const int base = seg * SEGLEN + t * 4;
    #pragma unroll
    for (int it = 0; it < SEGLEN / (256 * 4); ++it) {
        const int p = base + it * (256 * 4);
        const float4 a  = *(const float4*)(x0p + p);
        const float4 bb = *(const float4*)(x1p + p);
        const float ax[4] = {a.x, a.y, a.z, a.w};
        const float bx[4] = {bb.x, bb.y, bb.z, bb.w};
        #pragma unroll
        for (int e = 0; e < 4; ++e) {
            const float m  = fmaxf(ax[e], bx[e]);
            const float e0 = expf(ax[e] - m);
            const float e1 = expf(bx[e] - m);
            const float v  = (c == 0 ? e0 : e1) / (e0 + e1);
            const int p2 = p + e;
            if (better(v, p2, v0, i0)) { v1 = v0; i1 = i0; v0 = v; i0 = p2; }
            else if (better(v, p2, v1, i1)) { v1 = v; i1 = p2; }
        }
    }

    // --- replaced reduction: 64-lane in-register butterfly ---
    #pragma unroll
    for (int m = 1; m < 64; m <<= 1) {
        float o0 = __shfl_xor(v0, m), o1 = __shfl_xor(v1, m);
        int  oi0 = __shfl_xor(i0, m), oi1 = __shfl_xor(i1, m);
        merge2(v0, i0, v1, i1, o0, oi0, o1, oi1);
    }

    // cross-wave: 4 wave partials -> LDS -> t0 merges
    __shared__ float sv[4][2];
    __shared__ int   si[4][2];
    const int wave = t >> 6;
    if ((t & 63) == 0) {
        sv[wave][0] = v0; sv[wave][1] = v1;
        si[wave][0] = i0; si[wave][1] = i1;
    }
    __syncthreads();
    if (t == 0) {
        float a0 = sv[0][0], a1 = sv[0][1];
        int  ia0 = si[0][0], ia1 = si[0][1];
        #pragma unroll
        for (int wv = 1; wv < 4; ++wv) {
            merge2(a0, ia0, a1, ia1, sv[wv][0], si[wv][0], sv[wv][1], si[wv][1]);
        }
        ws_v[(row * SEGS + seg) * 2 + 0] = a0;
        ws_v[(row * SEGS + seg) * 2 + 1] = a1;
        ws_i[(row * SEGS + seg) * 2 + 0] = ia0;
        ws_i[(row * SEGS + seg) * 2 + 1] = ia1;
    }
}

// Stage 2: R1/R7 verbatim.
__global__ __launch_bounds__(128) void gather_out(
    const float* __restrict__ infeat,
    const float* __restrict__ labelTpesudo,
    const float* __restrict__ labelT,
    const float* __restrict__ FeatureDA,
    const float* __restrict__ ws_v, const int* __restrict__ ws_i,
    float* __restrict__ out)
{
    const int pi = blockIdx.x;           // 0..63
    const int c  = pi / (Bb * Kk);
    const int b  = (pi / Kk) % Bb;
    const int j  = pi % Kk;
    const int row = b * 2 + c;

    __shared__ float s_val;
    __shared__ int   s_idx;
    if (threadIdx.x == 0) {
        float bv0 = -INFINITY, bv1 = -INFINITY;
        int   bi0 = 0x7fffffff, bi1 = 0x7fffffff;
        for (int s2 = 0; s2 < SEGS; ++s2) {
            #pragma unroll
            for (int e = 0; e < 2; ++e) {
                const float v = ws_v[(row * SEGS + s2) * 2 + e];
                const int   i = ws_i[(row * SEGS + s2) * 2 + e];
                if (better(v, i, bv0, bi0)) { bv1 = bv0; bi1 = bi0; bv0 = v; bi0 = i; }
                else if (better(v, i, bv1, bi1)) { bv1 = v; bi1 = i; }
            }
        }
        s_val = (j == 0) ? bv0 : bv1;
        s_idx = (j == 0) ? bi0 : bi1;
    }
    __syncthreads();

    const int   idx = s_idx;
    const float val = s_val;
    const int py = idx >> 8;        // idx / W
    const int px = idx & (Ww - 1);  // idx % W
    const int t = threadIdx.x;

    // Output layout (flat float32, 8768 elems):
    //   [0,128)      classiferT   (64,2)
    //   [128,8320)   patchFeatDA  (64,128)
    //   [8320,8384)  labelTTrue   (64,1)
    //   [8384,8448)  labelpesudo  (64,1)
    //   [8448,8512)  provalue     (64,1)
    //   [8512,8768)  pointXY      (64,2,2) -> [px, min(px+31,255), py, min(py+31,255)]
    out[128 + pi * CF + t] = FeatureDA[((size_t)b * CF + t) * HWp + idx];
    if (t < 2) out[pi * 2 + t] = infeat[((size_t)b * 2 + t) * HWp + idx];
    if (t == 0) {
        out[8320 + pi] = labelT[(size_t)b * HWp + idx];
        out[8384 + pi] = labelTpesudo[(size_t)b * HWp + idx];
        out[8448 + pi] = val;
        out[8512 + pi * 4 + 0] = (float)px;
        out[8512 + pi * 4 + 1] = (float)min(px + 31, 255);
        out[8512 + pi * 4 + 2] = (float)py;
        out[8512 + pi * 4 + 3] = (float)min(py + 31, 255);
    }
}

extern "C" void kernel_launch(void* const* d_in, const int* in_sizes, int n_in,
                              void* d_out, int out_size, void* d_ws, size_t ws_size,
                              hipStream_t stream) {
    const float* infeat       = (const float*)d_in[0];
    const float* labelTpesudo = (const float*)d_in[1];
    const float* labelT       = (const float*)d_in[2];
    const float* FeatureDA    = (const float*)d_in[3];
    float* out = (float*)d_out;

    float* ws_v = (float*)d_ws;                                  // 32*SEGS*2 floats
    int*   ws_i = (int*)((char*)d_ws + 32 * SEGS * 2 * sizeof(float));

    dim3 g1(32, SEGS);
    top2_partial<<<g1, 256, 0, stream>>>(infeat, ws_v, ws_i);
    gather_out<<<64, 128, 0, stream>>>(infeat, labelTpesudo, labelT, FeatureDA,
                                       ws_v, ws_i, out);
}